// Round 3
// baseline (755.929 us; speedup 1.0000x reference)
//
#include <hip/hip_runtime.h>

// QuantizedLinear: out[m][n] = 0.01 * sum_k x[m][k]*(q[n][k]-8) + (0.01*0.047)*qbias[n]
// M=16384, N=4096, K=4096.
// R3: BK=64 + st_16x32-style 3-bit XOR swizzle (conflict-free ds_read_b128),
// 256x128 tile, 3-buffer ring, counted vmcnt(6) pipeline, setprio, XCD swizzle.

typedef __bf16 bf16x8 __attribute__((ext_vector_type(8)));
typedef float f32x4 __attribute__((ext_vector_type(4)));
typedef unsigned short u16;
typedef u16 u16x4 __attribute__((ext_vector_type(4)));
typedef u16 u16x8 __attribute__((ext_vector_type(8)));

static constexpr int Kdim = 4096;
static constexpr int Ndim = 4096;
static constexpr int BM = 256, BN = 128, BK = 64;
static constexpr int NKT = Kdim / BK;          // 64 K-tiles
static constexpr int ABUF = BM * BK;           // 16384 halfwords per A buffer
static constexpr int BBUF = BN * BK;           // 8192 halfwords per B buffer

__device__ __forceinline__ u16 f2bf(float f) {
  union { float f; unsigned u; } c; c.f = f;
  unsigned u = c.u;
  return (u16)((u + 0x7FFFu + ((u >> 16) & 1u)) >> 16);  // RNE
}

// ---- pre-pass 1: x fp32 -> bf16 ----
__global__ __launch_bounds__(256) void cvt_x_kernel(const float* __restrict__ x,
                                                    u16* __restrict__ xb, int n4) {
  int stride = gridDim.x * blockDim.x;
  for (int i = blockIdx.x * blockDim.x + threadIdx.x; i < n4; i += stride) {
    float4 v = reinterpret_cast<const float4*>(x)[i];
    u16x4 o;
    o.x = f2bf(v.x); o.y = f2bf(v.y); o.z = f2bf(v.z); o.w = f2bf(v.w);
    reinterpret_cast<u16x4*>(xb)[i] = o;
  }
}

// ---- pre-pass 2: packed nibbles -> bf16 integer weights (q-8), exact ----
__global__ __launch_bounds__(256) void dequant_w_kernel(const int* __restrict__ pw,
                                                        u16* __restrict__ wb, int n4) {
  int stride = gridDim.x * blockDim.x;
  for (int i = blockIdx.x * blockDim.x + threadIdx.x; i < n4; i += stride) {
    int4 v = reinterpret_cast<const int4*>(pw)[i];
    int a[4] = {v.x, v.y, v.z, v.w};
    u16x8 o;
#pragma unroll
    for (int j = 0; j < 4; ++j) {
      o[2 * j]     = f2bf((float)((a[j] & 15) - 8));
      o[2 * j + 1] = f2bf((float)(((a[j] >> 4) & 15) - 8));
    }
    reinterpret_cast<u16x8*>(wb)[i] = o;
  }
}

__device__ __forceinline__ void gload16(const u16* g, const u16* l) {
  __builtin_amdgcn_global_load_lds(
      (const __attribute__((address_space(1))) void*)g,
      (__attribute__((address_space(3))) void*)l,
      16, 0, 0);
}

// ---- main GEMM ----
__global__ __launch_bounds__(512, 2) void gemm_kernel(const u16* __restrict__ A,
                                                      const u16* __restrict__ B,
                                                      const int* __restrict__ qbias,
                                                      float* __restrict__ C,
                                                      int Mtiles) {
  extern __shared__ u16 smem[];
  u16* As = smem;                    // 3 x 256x64 halfwords = 96 KiB
  u16* Bs = smem + 3 * ABUF;         // 3 x 128x64 halfwords = 48 KiB

  const int tid = threadIdx.x;
  const int lane = tid & 63;
  const int wave = tid >> 6;
  const int wm = wave >> 1, wn = wave & 1;   // 4 (M) x 2 (N) waves, each 64x64

  // T1: XCD-aware chunked swizzle; grid = 2048 (multiple of 8)
  const int cpx = gridDim.x >> 3;
  const int bid = blockIdx.x;
  const int swz = (bid & 7) * cpx + (bid >> 3);
  const int by = swz % Mtiles;   // fast index -> same W-panel within an XCD chunk
  const int bx = swz / Mtiles;
  const int m0 = by * BM, n0 = bx * BN;

  // ---- staging geometry (source carries inverse of the LDS read swizzle) ----
  // granule g of a tile stage = load_i*512 + tid; row r = g>>3, phys slot p = g&7 (=tid&7).
  // stored logical slot s_log = p ^ (r&7) = (tid&7) ^ ((tid>>3)&7).
  const int srow = tid >> 3;
  const int fcol = (((tid & 7) ^ (srow & 7)) << 3);  // halfword col offset 0..56
  const u16* pa[4];
#pragma unroll
  for (int i = 0; i < 4; ++i)
    pa[i] = A + (size_t)(m0 + i * 64 + srow) * Kdim + fcol;
  const u16* pb[2];
#pragma unroll
  for (int i = 0; i < 2; ++i)
    pb[i] = B + (size_t)(n0 + i * 64 + srow) * Kdim + fcol;
  // wave-uniform LDS dest halfword offsets per load_i
  const int wbase = (tid & 0x1C0) * 8;               // wave*64 granules *8 h
  // dest offset for load i = (i*512 granules)*8 + wbase

  // ---- ds_read geometry: phys slot = s_log ^ (row&7), row&7 == lane&7 ----
  const int rowh = lane & 15;        // row within 16-row fragment
  const int e0 = ((lane >> 4) ^ (lane & 7)) << 3;    // kh=0 phys slot * 8
  const int e1 = e0 ^ 32;                            // kh=1 (s_log bit2 flips)
  const int aoff = (wm * 64 + rowh) * 64;            // halfword row base (A)
  const int boff = (wn * 64 + rowh) * 64;            // (B)

  f32x4 acc[4][4] = {};

  // ---- prologue: stage tiles 0,1 (6 loads each: A0..A3,B0,B1) ----
#pragma unroll
  for (int tt = 0; tt < 2; ++tt) {
    const u16* aW = As + tt * ABUF;
    const u16* bW = Bs + tt * BBUF;
    const int ko = tt * BK;
#pragma unroll
    for (int i = 0; i < 4; ++i) gload16(pa[i] + ko, aW + i * 4096 + wbase);
#pragma unroll
    for (int i = 0; i < 2; ++i) gload16(pb[i] + ko, bW + i * 4096 + wbase);
  }
  asm volatile("s_waitcnt vmcnt(6)" ::: "memory");   // tile 0 landed; tile 1 in flight
  __builtin_amdgcn_s_barrier();

  int rbuf = 0, wbuf = 2;
  for (int t = 0; t < NKT; ++t) {
    const u16* aL = As + rbuf * ABUF;
    const u16* bL = Bs + rbuf * BBUF;
    const u16* aW = As + wbuf * ABUF;
    const u16* bW = Bs + wbuf * BBUF;
    const bool st = (t + 2) < NKT;
    const int ko = (t + 2) * BK;

    // ---------- phase A: k-half 0 ----------
    bf16x8 af[4], bf[4];
#pragma unroll
    for (int m = 0; m < 4; ++m)
      af[m] = *(const bf16x8*)(aL + aoff + m * 1024 + e0);
#pragma unroll
    for (int n = 0; n < 4; ++n)
      bf[n] = *(const bf16x8*)(bL + boff + n * 1024 + e0);
    if (st) {
      gload16(pa[0] + ko, aW + 0 * 4096 + wbase);
      gload16(pa[1] + ko, aW + 1 * 4096 + wbase);
      gload16(pa[2] + ko, aW + 2 * 4096 + wbase);
    }
    __builtin_amdgcn_s_barrier();
    asm volatile("s_waitcnt lgkmcnt(0)" ::: "memory");
    __builtin_amdgcn_sched_barrier(0);
    __builtin_amdgcn_s_setprio(1);
#pragma unroll
    for (int m = 0; m < 4; ++m)
#pragma unroll
      for (int n = 0; n < 4; ++n)
        acc[m][n] = __builtin_amdgcn_mfma_f32_16x16x32_bf16(af[m], bf[n], acc[m][n], 0, 0, 0);
    __builtin_amdgcn_s_setprio(0);
    __builtin_amdgcn_sched_barrier(0);
    __builtin_amdgcn_s_barrier();

    // ---------- phase B: k-half 1 ----------
#pragma unroll
    for (int m = 0; m < 4; ++m)
      af[m] = *(const bf16x8*)(aL + aoff + m * 1024 + e1);
#pragma unroll
    for (int n = 0; n < 4; ++n)
      bf[n] = *(const bf16x8*)(bL + boff + n * 1024 + e1);
    if (st) {
      gload16(pa[3] + ko, aW + 3 * 4096 + wbase);
      gload16(pb[0] + ko, bW + 0 * 4096 + wbase);
      gload16(pb[1] + ko, bW + 1 * 4096 + wbase);
    }
    __builtin_amdgcn_s_barrier();
    asm volatile("s_waitcnt lgkmcnt(0)" ::: "memory");
    __builtin_amdgcn_sched_barrier(0);
    __builtin_amdgcn_s_setprio(1);
#pragma unroll
    for (int m = 0; m < 4; ++m)
#pragma unroll
      for (int n = 0; n < 4; ++n)
        acc[m][n] = __builtin_amdgcn_mfma_f32_16x16x32_bf16(af[m], bf[n], acc[m][n], 0, 0, 0);
    __builtin_amdgcn_s_setprio(0);
    __builtin_amdgcn_sched_barrier(0);

    // counted boundary wait: tile t+1 must be landed; keep tile t+2 in flight
    if (t + 2 < NKT)      asm volatile("s_waitcnt vmcnt(6)" ::: "memory");
    else if (t + 1 < NKT) asm volatile("s_waitcnt vmcnt(0)" ::: "memory");
    __builtin_amdgcn_s_barrier();

    rbuf = (rbuf == 2) ? 0 : rbuf + 1;
    wbuf = (wbuf == 2) ? 0 : wbuf + 1;
  }

  // epilogue: C/D layout col=lane&15, row=(lane>>4)*4+j
  const float wscale = 0.01f;
  const float bscale = (float)(0.01 * 0.047);
  const int col0 = n0 + wn * 64 + (lane & 15);
  const int row0 = m0 + wm * 64 + ((lane >> 4) << 2);
#pragma unroll
  for (int n = 0; n < 4; ++n) {
    const int col = col0 + n * 16;
    const float bias = bscale * (float)qbias[col];
#pragma unroll
    for (int m = 0; m < 4; ++m) {
      const int rr = row0 + m * 16;
#pragma unroll
      for (int j = 0; j < 4; ++j)
        C[(size_t)(rr + j) * Ndim + col] = wscale * acc[m][n][j] + bias;
    }
  }
}

extern "C" void kernel_launch(void* const* d_in, const int* in_sizes, int n_in,
                              void* d_out, int out_size, void* d_ws, size_t ws_size,
                              hipStream_t stream) {
  const float* x  = (const float*)d_in[0];
  const int*   pw = (const int*)d_in[1];
  const int*   qb = (const int*)d_in[2];
  float* out = (float*)d_out;

  const int M = in_sizes[0] / Kdim;  // 16384

  u16* xb = (u16*)d_ws;                                  // M*K bf16
  u16* wb = (u16*)((char*)d_ws + (size_t)M * Kdim * 2);  // N*K bf16

  cvt_x_kernel<<<2048, 256, 0, stream>>>(x, xb, M * Kdim / 4);
  dequant_w_kernel<<<1024, 256, 0, stream>>>(pw, wb, Ndim * Kdim / 8);

  const int Mtiles = M / BM;                     // 64
  const int nwg = Mtiles * (Ndim / BN);          // 2048, multiple of 8
  static const size_t lds_bytes = (3u * ABUF + 3u * BBUF) * sizeof(u16);  // 144 KiB
  (void)hipFuncSetAttribute((const void*)gemm_kernel,
                            hipFuncAttributeMaxDynamicSharedMemorySize,
                            (int)lds_bytes);
  gemm_kernel<<<nwg, 512, lds_bytes, stream>>>(xb, wb, qb, out, Mtiles);
}

// Round 4
// 570.768 us; speedup vs baseline: 1.3244x; 1.3244x over previous
//
#include <hip/hip_runtime.h>

// QuantizedLinear: out[m][n] = 0.01 * sum_k x[m][k]*(q[n][k]-8) + (0.01*0.047)*qbias[n]
// M=16384, N=4096, K=4096.
// R4: 256x256 tile, BK=64 zero-conflict XOR swizzle (R3-verified), asymmetric ring:
// A x3 buffers (prefetch distance 2, counted vmcnt(4) across boundaries),
// B x2 buffers (intra-tile prefetch). 4 phases/K-tile, setprio, XCD swizzle.
// LDS = 5 x 32KiB = 160 KiB exactly.

typedef __bf16 bf16x8 __attribute__((ext_vector_type(8)));
typedef float f32x4 __attribute__((ext_vector_type(4)));
typedef unsigned short u16;
typedef u16 u16x4 __attribute__((ext_vector_type(4)));
typedef u16 u16x8 __attribute__((ext_vector_type(8)));

static constexpr int Kdim = 4096;
static constexpr int Ndim = 4096;
static constexpr int BM = 256, BN = 256, BK = 64;
static constexpr int NKT = Kdim / BK;          // 64 K-tiles
static constexpr int TBUF = BM * BK;           // 16384 halfwords = 32 KiB per buffer

__device__ __forceinline__ u16 f2bf(float f) {
  union { float f; unsigned u; } c; c.f = f;
  unsigned u = c.u;
  return (u16)((u + 0x7FFFu + ((u >> 16) & 1u)) >> 16);  // RNE
}

// ---- pre-pass 1: x fp32 -> bf16 ----
__global__ __launch_bounds__(256) void cvt_x_kernel(const float* __restrict__ x,
                                                    u16* __restrict__ xb, int n4) {
  int stride = gridDim.x * blockDim.x;
  for (int i = blockIdx.x * blockDim.x + threadIdx.x; i < n4; i += stride) {
    float4 v = reinterpret_cast<const float4*>(x)[i];
    u16x4 o;
    o.x = f2bf(v.x); o.y = f2bf(v.y); o.z = f2bf(v.z); o.w = f2bf(v.w);
    reinterpret_cast<u16x4*>(xb)[i] = o;
  }
}

// ---- pre-pass 2: packed nibbles -> bf16 integer weights (q-8), exact ----
__global__ __launch_bounds__(256) void dequant_w_kernel(const int* __restrict__ pw,
                                                        u16* __restrict__ wb, int n4) {
  int stride = gridDim.x * blockDim.x;
  for (int i = blockIdx.x * blockDim.x + threadIdx.x; i < n4; i += stride) {
    int4 v = reinterpret_cast<const int4*>(pw)[i];
    int a[4] = {v.x, v.y, v.z, v.w};
    u16x8 o;
#pragma unroll
    for (int j = 0; j < 4; ++j) {
      o[2 * j]     = f2bf((float)((a[j] & 15) - 8));
      o[2 * j + 1] = f2bf((float)(((a[j] >> 4) & 15) - 8));
    }
    reinterpret_cast<u16x8*>(wb)[i] = o;
  }
}

__device__ __forceinline__ void gload16(const u16* g, const u16* l) {
  __builtin_amdgcn_global_load_lds(
      (const __attribute__((address_space(1))) void*)g,
      (__attribute__((address_space(3))) void*)l,
      16, 0, 0);
}

// ---- main GEMM ----
__global__ __launch_bounds__(512, 2) void gemm_kernel(const u16* __restrict__ A,
                                                      const u16* __restrict__ B,
                                                      const int* __restrict__ qbias,
                                                      float* __restrict__ C,
                                                      int Mtiles) {
  extern __shared__ u16 smem[];
  u16* As = smem;                    // 3 x 256x64 = 96 KiB (ring of 3)
  u16* Bs = smem + 3 * TBUF;         // 2 x 256x64 = 64 KiB (ring of 2)

  const int tid = threadIdx.x;
  const int lane = tid & 63;
  const int wave = tid >> 6;
  const int wm = wave >> 2, wn = wave & 3;   // 2 (M) x 4 (N) waves, each 128x64

  // T1: XCD-aware chunked swizzle; grid = 1024 (multiple of 8); by fast -> shared B panel
  const int cpx = gridDim.x >> 3;
  const int bid = blockIdx.x;
  const int swz = (bid & 7) * cpx + (bid >> 3);
  const int by = swz % Mtiles;
  const int bx = swz / Mtiles;
  const int m0 = by * BM, n0 = bx * BN;

  // ---- staging geometry (source carries inverse of the read swizzle) ----
  // granule = tid: row srow = tid>>3 (64 rows/gload), phys slot = tid&7,
  // stored logical slot = (tid&7) ^ (srow&7)  [rows per gload chunk are +64 -> &7 invariant]
  const int srow = tid >> 3;
  const int fcol = (((tid & 7) ^ (srow & 7)) << 3);  // halfword col offset
  const u16* pa[4];
  const u16* pb[4];
#pragma unroll
  for (int i = 0; i < 4; ++i) {
    pa[i] = A + (size_t)(m0 + i * 64 + srow) * Kdim + fcol;
    pb[i] = B + (size_t)(n0 + i * 64 + srow) * Kdim + fcol;
  }
  const int wbase = (tid & 0x1C0) * 8;   // wave-uniform LDS halfword base (HW adds lane*16B)

  // ---- ds_read geometry: phys slot = s_log ^ (row&7); row&7 == lane&7 ----
  const int e0 = ((lane >> 4) ^ (lane & 7)) << 3;    // k-half 0 slot offset (halfwords)
  const int e1 = e0 ^ 32;                            // k-half 1
  const int arow = (wm * 128 + (lane & 15)) * 64;    // A halfword row base
  const int brow = (wn * 64 + (lane & 15)) * 64;     // B halfword row base

  f32x4 acc[8][4] = {};

  // ---- prologue: B(0), A(0), A(1); vmcnt(4) leaves A(1) in flight ----
#pragma unroll
  for (int i = 0; i < 4; ++i) gload16(pb[i], Bs + i * 4096 + wbase);
#pragma unroll
  for (int i = 0; i < 4; ++i) gload16(pa[i], As + i * 4096 + wbase);
#pragma unroll
  for (int i = 0; i < 4; ++i) gload16(pa[i] + BK, As + TBUF + i * 4096 + wbase);
  asm volatile("s_waitcnt vmcnt(4)" ::: "memory");
  __builtin_amdgcn_s_barrier();

  int rbuf = 0;
  for (int t = 0; t < NKT; ++t) {
    const u16* aL = As + rbuf * TBUF;
    const u16* bL = Bs + (t & 1) * TBUF;
    const u16* aW = As + ((rbuf + 2) % 3) * TBUF;     // A(t+2) dest
    const u16* bW = Bs + ((t + 1) & 1) * TBUF;        // B(t+1) dest
    const bool stb = (t + 1) < NKT;
    const bool sta = (t + 2) < NKT;
    const int kob = (t + 1) * BK;
    const int koa = (t + 2) * BK;

    bf16x8 af[4], bf[4][2];

#define PHASE_TAIL(ACC_BASE, KH)                                              \
    __builtin_amdgcn_s_barrier();                                             \
    asm volatile("s_waitcnt lgkmcnt(0)" ::: "memory");                        \
    __builtin_amdgcn_sched_barrier(0);                                        \
    __builtin_amdgcn_s_setprio(1);                                            \
    _Pragma("unroll")                                                         \
    for (int m = 0; m < 4; ++m)                                               \
      _Pragma("unroll")                                                       \
      for (int n = 0; n < 4; ++n)                                             \
        acc[(ACC_BASE) + m][n] = __builtin_amdgcn_mfma_f32_16x16x32_bf16(     \
            af[m], bf[n][KH], acc[(ACC_BASE) + m][n], 0, 0, 0);               \
    __builtin_amdgcn_s_setprio(0);                                            \
    __builtin_amdgcn_sched_barrier(0);                                        \
    __builtin_amdgcn_s_barrier();

    // ---- phase 0: mh=0, kh=0 (also load all B frags for both k-halves) ----
#pragma unroll
    for (int m = 0; m < 4; ++m)
      af[m] = *(const bf16x8*)(aL + arow + m * 1024 + e0);
#pragma unroll
    for (int n = 0; n < 4; ++n) {
      bf[n][0] = *(const bf16x8*)(bL + brow + n * 1024 + e0);
      bf[n][1] = *(const bf16x8*)(bL + brow + n * 1024 + e1);
    }
    if (stb) { gload16(pb[0] + kob, bW + 0 * 4096 + wbase);
               gload16(pb[1] + kob, bW + 1 * 4096 + wbase); }
    PHASE_TAIL(0, 0)

    // ---- phase 1: mh=0, kh=1 ----
#pragma unroll
    for (int m = 0; m < 4; ++m)
      af[m] = *(const bf16x8*)(aL + arow + m * 1024 + e1);
    if (stb) { gload16(pb[2] + kob, bW + 2 * 4096 + wbase);
               gload16(pb[3] + kob, bW + 3 * 4096 + wbase); }
    PHASE_TAIL(0, 1)

    // ---- phase 2: mh=1, kh=0 ----
#pragma unroll
    for (int m = 0; m < 4; ++m)
      af[m] = *(const bf16x8*)(aL + arow + 4096 + m * 1024 + e0);
    if (sta) { gload16(pa[0] + koa, aW + 0 * 4096 + wbase);
               gload16(pa[1] + koa, aW + 1 * 4096 + wbase); }
    PHASE_TAIL(4, 0)

    // ---- phase 3: mh=1, kh=1 ----
#pragma unroll
    for (int m = 0; m < 4; ++m)
      af[m] = *(const bf16x8*)(aL + arow + 4096 + m * 1024 + e1);
    if (sta) { gload16(pa[2] + koa, aW + 2 * 4096 + wbase);
               gload16(pa[3] + koa, aW + 3 * 4096 + wbase); }
    __builtin_amdgcn_s_barrier();
    asm volatile("s_waitcnt lgkmcnt(0)" ::: "memory");
    __builtin_amdgcn_sched_barrier(0);
    __builtin_amdgcn_s_setprio(1);
#pragma unroll
    for (int m = 0; m < 4; ++m)
#pragma unroll
      for (int n = 0; n < 4; ++n)
        acc[4 + m][n] = __builtin_amdgcn_mfma_f32_16x16x32_bf16(
            af[m], bf[n][1], acc[4 + m][n], 0, 0, 0);
    __builtin_amdgcn_s_setprio(0);
    __builtin_amdgcn_sched_barrier(0);

    // boundary: B(t+1) + A(t+1) landed; A(t+2) (newest 4) stays in flight
    if (sta)      asm volatile("s_waitcnt vmcnt(4)" ::: "memory");
    else if (stb) asm volatile("s_waitcnt vmcnt(0)" ::: "memory");
    __builtin_amdgcn_s_barrier();

    rbuf = (rbuf == 2) ? 0 : rbuf + 1;
#undef PHASE_TAIL
  }

  // epilogue: C/D layout col=lane&15, row=(lane>>4)*4+j
  const float wscale = 0.01f;
  const float bscale = (float)(0.01 * 0.047);
  const int col0 = n0 + wn * 64 + (lane & 15);
  const int row0 = m0 + wm * 128 + ((lane >> 4) << 2);
#pragma unroll
  for (int n = 0; n < 4; ++n) {
    const int col = col0 + n * 16;
    const float bias = bscale * (float)qbias[col];
#pragma unroll
    for (int m = 0; m < 8; ++m) {
      const int rr = row0 + m * 16;
#pragma unroll
      for (int j = 0; j < 4; ++j)
        C[(size_t)(rr + j) * Ndim + col] = wscale * acc[m][n][j] + bias;
    }
  }
}

extern "C" void kernel_launch(void* const* d_in, const int* in_sizes, int n_in,
                              void* d_out, int out_size, void* d_ws, size_t ws_size,
                              hipStream_t stream) {
  const float* x  = (const float*)d_in[0];
  const int*   pw = (const int*)d_in[1];
  const int*   qb = (const int*)d_in[2];
  float* out = (float*)d_out;

  const int M = in_sizes[0] / Kdim;  // 16384

  u16* xb = (u16*)d_ws;                                  // M*K bf16
  u16* wb = (u16*)((char*)d_ws + (size_t)M * Kdim * 2);  // N*K bf16

  cvt_x_kernel<<<2048, 256, 0, stream>>>(x, xb, M * Kdim / 4);
  dequant_w_kernel<<<1024, 256, 0, stream>>>(pw, wb, Ndim * Kdim / 8);

  const int Mtiles = M / BM;                     // 64
  const int nwg = Mtiles * (Ndim / BN);          // 1024, multiple of 8
  static const size_t lds_bytes = 5u * TBUF * sizeof(u16);  // 160 KiB exactly
  (void)hipFuncSetAttribute((const void*)gemm_kernel,
                            hipFuncAttributeMaxDynamicSharedMemorySize,
                            (int)lds_bytes);
  gemm_kernel<<<nwg, 512, lds_bytes, stream>>>(xb, wb, qb, out, Mtiles);
}

// Round 5
// 550.423 us; speedup vs baseline: 1.3734x; 1.0370x over previous
//
#include <hip/hip_runtime.h>

// QuantizedLinear: out[m][n] = 0.01 * sum_k x[m][k]*(q[n][k]-8) + (0.01*0.047)*qbias[n]
// M=16384, N=4096, K=4096.
// R5: R4 + flipped XCD swizzle (bx fast within chunk -> A panel L2-resident,
// A HBM-fetched once; B is L3-resident). Rest identical to R4:
// 256x256 tile, BK=64 zero-conflict XOR swizzle, A x3 / B x2 ring,
// counted vmcnt(4), 4 phases/K-tile, setprio. LDS = 160 KiB.

typedef __bf16 bf16x8 __attribute__((ext_vector_type(8)));
typedef float f32x4 __attribute__((ext_vector_type(4)));
typedef unsigned short u16;
typedef u16 u16x4 __attribute__((ext_vector_type(4)));
typedef u16 u16x8 __attribute__((ext_vector_type(8)));

static constexpr int Kdim = 4096;
static constexpr int Ndim = 4096;
static constexpr int BM = 256, BN = 256, BK = 64;
static constexpr int NKT = Kdim / BK;          // 64 K-tiles
static constexpr int TBUF = BM * BK;           // 16384 halfwords = 32 KiB per buffer

__device__ __forceinline__ u16 f2bf(float f) {
  union { float f; unsigned u; } c; c.f = f;
  unsigned u = c.u;
  return (u16)((u + 0x7FFFu + ((u >> 16) & 1u)) >> 16);  // RNE
}

// ---- pre-pass 1: x fp32 -> bf16 ----
__global__ __launch_bounds__(256) void cvt_x_kernel(const float* __restrict__ x,
                                                    u16* __restrict__ xb, int n4) {
  int stride = gridDim.x * blockDim.x;
  for (int i = blockIdx.x * blockDim.x + threadIdx.x; i < n4; i += stride) {
    float4 v = reinterpret_cast<const float4*>(x)[i];
    u16x4 o;
    o.x = f2bf(v.x); o.y = f2bf(v.y); o.z = f2bf(v.z); o.w = f2bf(v.w);
    reinterpret_cast<u16x4*>(xb)[i] = o;
  }
}

// ---- pre-pass 2: packed nibbles -> bf16 integer weights (q-8), exact ----
__global__ __launch_bounds__(256) void dequant_w_kernel(const int* __restrict__ pw,
                                                        u16* __restrict__ wb, int n4) {
  int stride = gridDim.x * blockDim.x;
  for (int i = blockIdx.x * blockDim.x + threadIdx.x; i < n4; i += stride) {
    int4 v = reinterpret_cast<const int4*>(pw)[i];
    int a[4] = {v.x, v.y, v.z, v.w};
    u16x8 o;
#pragma unroll
    for (int j = 0; j < 4; ++j) {
      o[2 * j]     = f2bf((float)((a[j] & 15) - 8));
      o[2 * j + 1] = f2bf((float)(((a[j] >> 4) & 15) - 8));
    }
    reinterpret_cast<u16x8*>(wb)[i] = o;
  }
}

__device__ __forceinline__ void gload16(const u16* g, const u16* l) {
  __builtin_amdgcn_global_load_lds(
      (const __attribute__((address_space(1))) void*)g,
      (__attribute__((address_space(3))) void*)l,
      16, 0, 0);
}

// ---- main GEMM ----
__global__ __launch_bounds__(512, 2) void gemm_kernel(const u16* __restrict__ A,
                                                      const u16* __restrict__ B,
                                                      const int* __restrict__ qbias,
                                                      float* __restrict__ C,
                                                      int Ntiles) {
  extern __shared__ u16 smem[];
  u16* As = smem;                    // 3 x 256x64 = 96 KiB (ring of 3)
  u16* Bs = smem + 3 * TBUF;         // 2 x 256x64 = 64 KiB (ring of 2)

  const int tid = threadIdx.x;
  const int lane = tid & 63;
  const int wave = tid >> 6;
  const int wm = wave >> 2, wn = wave & 3;   // 2 (M) x 4 (N) waves, each 128x64

  // T1 (flipped): bx fast within XCD chunk -> A panel L2-resident per XCD,
  // A fetched from HBM once total; B panels stream but are L3-resident.
  const int cpx = gridDim.x >> 3;
  const int bid = blockIdx.x;
  const int swz = (bid & 7) * cpx + (bid >> 3);
  const int bx = swz % Ntiles;
  const int by = swz / Ntiles;
  const int m0 = by * BM, n0 = bx * BN;

  // ---- staging geometry (source carries inverse of the read swizzle) ----
  const int srow = tid >> 3;
  const int fcol = (((tid & 7) ^ (srow & 7)) << 3);  // halfword col offset
  const u16* pa[4];
  const u16* pb[4];
#pragma unroll
  for (int i = 0; i < 4; ++i) {
    pa[i] = A + (size_t)(m0 + i * 64 + srow) * Kdim + fcol;
    pb[i] = B + (size_t)(n0 + i * 64 + srow) * Kdim + fcol;
  }
  const int wbase = (tid & 0x1C0) * 8;   // wave-uniform LDS halfword base (HW adds lane*16B)

  // ---- ds_read geometry: phys slot = s_log ^ (row&7); row&7 == lane&7 ----
  const int e0 = ((lane >> 4) ^ (lane & 7)) << 3;    // k-half 0 slot offset (halfwords)
  const int e1 = e0 ^ 32;                            // k-half 1
  const int arow = (wm * 128 + (lane & 15)) * 64;    // A halfword row base
  const int brow = (wn * 64 + (lane & 15)) * 64;     // B halfword row base

  f32x4 acc[8][4] = {};

  // ---- prologue: B(0), A(0), A(1); vmcnt(4) leaves A(1) in flight ----
#pragma unroll
  for (int i = 0; i < 4; ++i) gload16(pb[i], Bs + i * 4096 + wbase);
#pragma unroll
  for (int i = 0; i < 4; ++i) gload16(pa[i], As + i * 4096 + wbase);
#pragma unroll
  for (int i = 0; i < 4; ++i) gload16(pa[i] + BK, As + TBUF + i * 4096 + wbase);
  asm volatile("s_waitcnt vmcnt(4)" ::: "memory");
  __builtin_amdgcn_s_barrier();

  int rbuf = 0;
  for (int t = 0; t < NKT; ++t) {
    const u16* aL = As + rbuf * TBUF;
    const u16* bL = Bs + (t & 1) * TBUF;
    const u16* aW = As + ((rbuf + 2) % 3) * TBUF;     // A(t+2) dest
    const u16* bW = Bs + ((t + 1) & 1) * TBUF;        // B(t+1) dest
    const bool stb = (t + 1) < NKT;
    const bool sta = (t + 2) < NKT;
    const int kob = (t + 1) * BK;
    const int koa = (t + 2) * BK;

    bf16x8 af[4], bf[4][2];

#define PHASE_TAIL(ACC_BASE, KH)                                              \
    __builtin_amdgcn_s_barrier();                                             \
    asm volatile("s_waitcnt lgkmcnt(0)" ::: "memory");                        \
    __builtin_amdgcn_sched_barrier(0);                                        \
    __builtin_amdgcn_s_setprio(1);                                            \
    _Pragma("unroll")                                                         \
    for (int m = 0; m < 4; ++m)                                               \
      _Pragma("unroll")                                                       \
      for (int n = 0; n < 4; ++n)                                             \
        acc[(ACC_BASE) + m][n] = __builtin_amdgcn_mfma_f32_16x16x32_bf16(     \
            af[m], bf[n][KH], acc[(ACC_BASE) + m][n], 0, 0, 0);               \
    __builtin_amdgcn_s_setprio(0);                                            \
    __builtin_amdgcn_sched_barrier(0);                                        \
    __builtin_amdgcn_s_barrier();

    // ---- phase 0: mh=0, kh=0 (also load all B frags for both k-halves) ----
#pragma unroll
    for (int m = 0; m < 4; ++m)
      af[m] = *(const bf16x8*)(aL + arow + m * 1024 + e0);
#pragma unroll
    for (int n = 0; n < 4; ++n) {
      bf[n][0] = *(const bf16x8*)(bL + brow + n * 1024 + e0);
      bf[n][1] = *(const bf16x8*)(bL + brow + n * 1024 + e1);
    }
    if (stb) { gload16(pb[0] + kob, bW + 0 * 4096 + wbase);
               gload16(pb[1] + kob, bW + 1 * 4096 + wbase); }
    PHASE_TAIL(0, 0)

    // ---- phase 1: mh=0, kh=1 ----
#pragma unroll
    for (int m = 0; m < 4; ++m)
      af[m] = *(const bf16x8*)(aL + arow + m * 1024 + e1);
    if (stb) { gload16(pb[2] + kob, bW + 2 * 4096 + wbase);
               gload16(pb[3] + kob, bW + 3 * 4096 + wbase); }
    PHASE_TAIL(0, 1)

    // ---- phase 2: mh=1, kh=0 ----
#pragma unroll
    for (int m = 0; m < 4; ++m)
      af[m] = *(const bf16x8*)(aL + arow + 4096 + m * 1024 + e0);
    if (sta) { gload16(pa[0] + koa, aW + 0 * 4096 + wbase);
               gload16(pa[1] + koa, aW + 1 * 4096 + wbase); }
    PHASE_TAIL(4, 0)

    // ---- phase 3: mh=1, kh=1 ----
#pragma unroll
    for (int m = 0; m < 4; ++m)
      af[m] = *(const bf16x8*)(aL + arow + 4096 + m * 1024 + e1);
    if (sta) { gload16(pa[2] + koa, aW + 2 * 4096 + wbase);
               gload16(pa[3] + koa, aW + 3 * 4096 + wbase); }
    __builtin_amdgcn_s_barrier();
    asm volatile("s_waitcnt lgkmcnt(0)" ::: "memory");
    __builtin_amdgcn_sched_barrier(0);
    __builtin_amdgcn_s_setprio(1);
#pragma unroll
    for (int m = 0; m < 4; ++m)
#pragma unroll
      for (int n = 0; n < 4; ++n)
        acc[4 + m][n] = __builtin_amdgcn_mfma_f32_16x16x32_bf16(
            af[m], bf[n][1], acc[4 + m][n], 0, 0, 0);
    __builtin_amdgcn_s_setprio(0);
    __builtin_amdgcn_sched_barrier(0);

    // boundary: B(t+1) + A(t+1) landed; A(t+2) (newest 4) stays in flight
    if (sta)      asm volatile("s_waitcnt vmcnt(4)" ::: "memory");
    else if (stb) asm volatile("s_waitcnt vmcnt(0)" ::: "memory");
    __builtin_amdgcn_s_barrier();

    rbuf = (rbuf == 2) ? 0 : rbuf + 1;
#undef PHASE_TAIL
  }

  // epilogue: C/D layout col=lane&15, row=(lane>>4)*4+j
  const float wscale = 0.01f;
  const float bscale = (float)(0.01 * 0.047);
  const int col0 = n0 + wn * 64 + (lane & 15);
  const int row0 = m0 + wm * 128 + ((lane >> 4) << 2);
#pragma unroll
  for (int n = 0; n < 4; ++n) {
    const int col = col0 + n * 16;
    const float bias = bscale * (float)qbias[col];
#pragma unroll
    for (int m = 0; m < 8; ++m) {
      const int rr = row0 + m * 16;
#pragma unroll
      for (int j = 0; j < 4; ++j)
        C[(size_t)(rr + j) * Ndim + col] = wscale * acc[m][n][j] + bias;
    }
  }
}

extern "C" void kernel_launch(void* const* d_in, const int* in_sizes, int n_in,
                              void* d_out, int out_size, void* d_ws, size_t ws_size,
                              hipStream_t stream) {
  const float* x  = (const float*)d_in[0];
  const int*   pw = (const int*)d_in[1];
  const int*   qb = (const int*)d_in[2];
  float* out = (float*)d_out;

  const int M = in_sizes[0] / Kdim;  // 16384

  u16* xb = (u16*)d_ws;                                  // M*K bf16
  u16* wb = (u16*)((char*)d_ws + (size_t)M * Kdim * 2);  // N*K bf16

  cvt_x_kernel<<<2048, 256, 0, stream>>>(x, xb, M * Kdim / 4);
  dequant_w_kernel<<<1024, 256, 0, stream>>>(pw, wb, Ndim * Kdim / 8);

  const int Ntiles = Ndim / BN;                  // 16
  const int nwg = (M / BM) * Ntiles;             // 1024, multiple of 8
  static const size_t lds_bytes = 5u * TBUF * sizeof(u16);  // 160 KiB exactly
  (void)hipFuncSetAttribute((const void*)gemm_kernel,
                            hipFuncAttributeMaxDynamicSharedMemorySize,
                            (int)lds_bytes);
  gemm_kernel<<<nwg, 512, lds_bytes, stream>>>(xb, wb, qb, out, Ntiles);
}

// Round 6
// 539.581 us; speedup vs baseline: 1.4010x; 1.0201x over previous
//
#include <hip/hip_runtime.h>

// QuantizedLinear: out[m][n] = 0.01 * sum_k x[m][k]*(q[n][k]-8) + (0.01*0.047)*qbias[n]
// M=16384, N=4096, K=4096.
// R6: R5 memory layout (256x256, BK=64 zero-conflict XOR swizzle, A x3/B x2 ring,
// flipped XCD swizzle) + barrier-free intra-tile register pipeline:
// only ONE s_barrier per K-tile (boundary). Counted lgkmcnt(4) between phases,
// counted vmcnt(4) at boundary. MFMA overlaps ds_read/gload issue.

typedef __bf16 bf16x8 __attribute__((ext_vector_type(8)));
typedef float f32x4 __attribute__((ext_vector_type(4)));
typedef unsigned short u16;
typedef u16 u16x4 __attribute__((ext_vector_type(4)));
typedef u16 u16x8 __attribute__((ext_vector_type(8)));

static constexpr int Kdim = 4096;
static constexpr int Ndim = 4096;
static constexpr int BM = 256, BN = 256, BK = 64;
static constexpr int NKT = Kdim / BK;          // 64 K-tiles
static constexpr int TBUF = BM * BK;           // 16384 halfwords = 32 KiB per buffer

__device__ __forceinline__ u16 f2bf(float f) {
  union { float f; unsigned u; } c; c.f = f;
  unsigned u = c.u;
  return (u16)((u + 0x7FFFu + ((u >> 16) & 1u)) >> 16);  // RNE
}

// ---- pre-pass 1: x fp32 -> bf16 ----
__global__ __launch_bounds__(256) void cvt_x_kernel(const float* __restrict__ x,
                                                    u16* __restrict__ xb, int n4) {
  int stride = gridDim.x * blockDim.x;
  for (int i = blockIdx.x * blockDim.x + threadIdx.x; i < n4; i += stride) {
    float4 v = reinterpret_cast<const float4*>(x)[i];
    u16x4 o;
    o.x = f2bf(v.x); o.y = f2bf(v.y); o.z = f2bf(v.z); o.w = f2bf(v.w);
    reinterpret_cast<u16x4*>(xb)[i] = o;
  }
}

// ---- pre-pass 2: packed nibbles -> bf16 integer weights (q-8), exact ----
__global__ __launch_bounds__(256) void dequant_w_kernel(const int* __restrict__ pw,
                                                        u16* __restrict__ wb, int n4) {
  int stride = gridDim.x * blockDim.x;
  for (int i = blockIdx.x * blockDim.x + threadIdx.x; i < n4; i += stride) {
    int4 v = reinterpret_cast<const int4*>(pw)[i];
    int a[4] = {v.x, v.y, v.z, v.w};
    u16x8 o;
#pragma unroll
    for (int j = 0; j < 4; ++j) {
      o[2 * j]     = f2bf((float)((a[j] & 15) - 8));
      o[2 * j + 1] = f2bf((float)(((a[j] >> 4) & 15) - 8));
    }
    reinterpret_cast<u16x8*>(wb)[i] = o;
  }
}

__device__ __forceinline__ void gload16(const u16* g, const u16* l) {
  __builtin_amdgcn_global_load_lds(
      (const __attribute__((address_space(1))) void*)g,
      (__attribute__((address_space(3))) void*)l,
      16, 0, 0);
}

// ---- main GEMM ----
__global__ __launch_bounds__(512, 2) void gemm_kernel(const u16* __restrict__ A,
                                                      const u16* __restrict__ B,
                                                      const int* __restrict__ qbias,
                                                      float* __restrict__ C,
                                                      int Ntiles) {
  extern __shared__ u16 smem[];
  u16* As = smem;                    // 3 x 256x64 = 96 KiB (ring of 3)
  u16* Bs = smem + 3 * TBUF;         // 2 x 256x64 = 64 KiB (ring of 2)

  const int tid = threadIdx.x;
  const int lane = tid & 63;
  const int wave = tid >> 6;
  const int wm = wave >> 2, wn = wave & 3;   // 2 (M) x 4 (N) waves, each 128x64

  // T1 (flipped): bx fast within XCD chunk -> A panel L2-resident per XCD.
  const int cpx = gridDim.x >> 3;
  const int bid = blockIdx.x;
  const int swz = (bid & 7) * cpx + (bid >> 3);
  const int bx = swz % Ntiles;
  const int by = swz / Ntiles;
  const int m0 = by * BM, n0 = bx * BN;

  // ---- staging geometry (source carries inverse of the read swizzle) ----
  const int srow = tid >> 3;
  const int fcol = (((tid & 7) ^ (srow & 7)) << 3);  // halfword col offset
  const u16* pa[4];
  const u16* pb[4];
#pragma unroll
  for (int i = 0; i < 4; ++i) {
    pa[i] = A + (size_t)(m0 + i * 64 + srow) * Kdim + fcol;
    pb[i] = B + (size_t)(n0 + i * 64 + srow) * Kdim + fcol;
  }
  const int wbase = (tid & 0x1C0) * 8;   // wave-uniform LDS halfword base (HW adds lane*16B)

  // ---- ds_read geometry: phys slot = s_log ^ (row&7); row&7 == lane&7 ----
  const int e0 = ((lane >> 4) ^ (lane & 7)) << 3;    // k-half 0 slot offset (halfwords)
  const int e1 = e0 ^ 32;                            // k-half 1
  const int arow = (wm * 128 + (lane & 15)) * 64;    // A halfword row base
  const int brow = (wn * 64 + (lane & 15)) * 64;     // B halfword row base

  f32x4 acc[8][4] = {};

  // ---- prologue: B(0), A(0), A(1); vmcnt(4) leaves A(1) in flight ----
#pragma unroll
  for (int i = 0; i < 4; ++i) gload16(pb[i], Bs + i * 4096 + wbase);
#pragma unroll
  for (int i = 0; i < 4; ++i) gload16(pa[i], As + i * 4096 + wbase);
#pragma unroll
  for (int i = 0; i < 4; ++i) gload16(pa[i] + BK, As + TBUF + i * 4096 + wbase);
  asm volatile("s_waitcnt vmcnt(4)" ::: "memory");
  __builtin_amdgcn_s_barrier();

  int rbuf = 0;
  for (int t = 0; t < NKT; ++t) {
    const u16* aL = As + rbuf * TBUF;
    const u16* bL = Bs + (t & 1) * TBUF;
    const u16* aW = As + ((rbuf + 2) % 3) * TBUF;     // A(t+2) dest
    const u16* bW = Bs + ((t + 1) & 1) * TBUF;        // B(t+1) dest
    const bool stb = (t + 1) < NKT;
    const bool sta = (t + 2) < NKT;
    const int kob = (t + 1) * BK;
    const int koa = (t + 2) * BK;

    bf16x8 a0[4], a1[4], bf[4][2];

    // ---- tile-start reads (12): a-frags m0-3 kh0, B all frags both k-halves ----
#pragma unroll
    for (int m = 0; m < 4; ++m)
      a0[m] = *(const bf16x8*)(aL + arow + m * 1024 + e0);
#pragma unroll
    for (int n = 0; n < 4; ++n)
      bf[n][0] = *(const bf16x8*)(bL + brow + n * 1024 + e0);
#pragma unroll
    for (int n = 0; n < 4; ++n)
      bf[n][1] = *(const bf16x8*)(bL + brow + n * 1024 + e1);

    // ---- P0: prefetch a1 (m4-7,kh0); stage 2xB; MFMA acc[0..3] x bf[.][0] ----
#pragma unroll
    for (int m = 0; m < 4; ++m)
      a1[m] = *(const bf16x8*)(aL + arow + 4096 + m * 1024 + e0);
    if (stb) { gload16(pb[0] + kob, bW + 0 * 4096 + wbase);
               gload16(pb[1] + kob, bW + 1 * 4096 + wbase); }
    asm volatile("s_waitcnt lgkmcnt(4)" ::: "memory");
    __builtin_amdgcn_sched_barrier(0);
    __builtin_amdgcn_s_setprio(1);
#pragma unroll
    for (int m = 0; m < 4; ++m)
#pragma unroll
      for (int n = 0; n < 4; ++n)
        acc[m][n] = __builtin_amdgcn_mfma_f32_16x16x32_bf16(a0[m], bf[n][0], acc[m][n], 0, 0, 0);
    __builtin_amdgcn_s_setprio(0);

    // ---- P1: prefetch a0' (m0-3,kh1); stage 2xB; MFMA acc[4..7] = a1 x bf[.][0] ----
#pragma unroll
    for (int m = 0; m < 4; ++m)
      a0[m] = *(const bf16x8*)(aL + arow + m * 1024 + e1);
    if (stb) { gload16(pb[2] + kob, bW + 2 * 4096 + wbase);
               gload16(pb[3] + kob, bW + 3 * 4096 + wbase); }
    asm volatile("s_waitcnt lgkmcnt(4)" ::: "memory");
    __builtin_amdgcn_sched_barrier(0);
    __builtin_amdgcn_s_setprio(1);
#pragma unroll
    for (int m = 0; m < 4; ++m)
#pragma unroll
      for (int n = 0; n < 4; ++n)
        acc[4 + m][n] = __builtin_amdgcn_mfma_f32_16x16x32_bf16(a1[m], bf[n][0], acc[4 + m][n], 0, 0, 0);
    __builtin_amdgcn_s_setprio(0);

    // ---- P2: prefetch a1' (m4-7,kh1); stage 2xA; MFMA acc[0..3] += a0 x bf[.][1] ----
#pragma unroll
    for (int m = 0; m < 4; ++m)
      a1[m] = *(const bf16x8*)(aL + arow + 4096 + m * 1024 + e1);
    if (sta) { gload16(pa[0] + koa, aW + 0 * 4096 + wbase);
               gload16(pa[1] + koa, aW + 1 * 4096 + wbase); }
    asm volatile("s_waitcnt lgkmcnt(4)" ::: "memory");
    __builtin_amdgcn_sched_barrier(0);
    __builtin_amdgcn_s_setprio(1);
#pragma unroll
    for (int m = 0; m < 4; ++m)
#pragma unroll
      for (int n = 0; n < 4; ++n)
        acc[m][n] = __builtin_amdgcn_mfma_f32_16x16x32_bf16(a0[m], bf[n][1], acc[m][n], 0, 0, 0);
    __builtin_amdgcn_s_setprio(0);

    // ---- P3: stage 2xA; drain reads; MFMA acc[4..7] += a1 x bf[.][1] ----
    if (sta) { gload16(pa[2] + koa, aW + 2 * 4096 + wbase);
               gload16(pa[3] + koa, aW + 3 * 4096 + wbase); }
    asm volatile("s_waitcnt lgkmcnt(0)" ::: "memory");
    __builtin_amdgcn_sched_barrier(0);
    __builtin_amdgcn_s_setprio(1);
#pragma unroll
    for (int m = 0; m < 4; ++m)
#pragma unroll
      for (int n = 0; n < 4; ++n)
        acc[4 + m][n] = __builtin_amdgcn_mfma_f32_16x16x32_bf16(a1[m], bf[n][1], acc[4 + m][n], 0, 0, 0);
    __builtin_amdgcn_s_setprio(0);
    __builtin_amdgcn_sched_barrier(0);

    // ---- boundary: A(t+1)+B(t+1) landed; A(t+2) (newest 4) stays in flight ----
    if (sta)      asm volatile("s_waitcnt vmcnt(4)" ::: "memory");
    else if (stb) asm volatile("s_waitcnt vmcnt(0)" ::: "memory");
    __builtin_amdgcn_s_barrier();

    rbuf = (rbuf == 2) ? 0 : rbuf + 1;
  }

  // epilogue: C/D layout col=lane&15, row=(lane>>4)*4+j
  const float wscale = 0.01f;
  const float bscale = (float)(0.01 * 0.047);
  const int col0 = n0 + wn * 64 + (lane & 15);
  const int row0 = m0 + wm * 128 + ((lane >> 4) << 2);
#pragma unroll
  for (int n = 0; n < 4; ++n) {
    const int col = col0 + n * 16;
    const float bias = bscale * (float)qbias[col];
#pragma unroll
    for (int m = 0; m < 8; ++m) {
      const int rr = row0 + m * 16;
#pragma unroll
      for (int j = 0; j < 4; ++j)
        C[(size_t)(rr + j) * Ndim + col] = wscale * acc[m][n][j] + bias;
    }
  }
}

extern "C" void kernel_launch(void* const* d_in, const int* in_sizes, int n_in,
                              void* d_out, int out_size, void* d_ws, size_t ws_size,
                              hipStream_t stream) {
  const float* x  = (const float*)d_in[0];
  const int*   pw = (const int*)d_in[1];
  const int*   qb = (const int*)d_in[2];
  float* out = (float*)d_out;

  const int M = in_sizes[0] / Kdim;  // 16384

  u16* xb = (u16*)d_ws;                                  // M*K bf16
  u16* wb = (u16*)((char*)d_ws + (size_t)M * Kdim * 2);  // N*K bf16

  cvt_x_kernel<<<2048, 256, 0, stream>>>(x, xb, M * Kdim / 4);
  dequant_w_kernel<<<1024, 256, 0, stream>>>(pw, wb, Ndim * Kdim / 8);

  const int Ntiles = Ndim / BN;                  // 16
  const int nwg = (M / BM) * Ntiles;             // 1024, multiple of 8
  static const size_t lds_bytes = 5u * TBUF * sizeof(u16);  // 160 KiB exactly
  (void)hipFuncSetAttribute((const void*)gemm_kernel,
                            hipFuncAttributeMaxDynamicSharedMemorySize,
                            (int)lds_bytes);
  gemm_kernel<<<nwg, 512, lds_bytes, stream>>>(xb, wb, qb, out, Ntiles);
}